// Round 10
// baseline (320.922 us; speedup 1.0000x reference)
//
#include <hip/hip_runtime.h>

#define NN 50000
#define NE 800000
#define NF 64
#define NL 3
#define PAD 64
#define NSLICE 8
#define SLICE_N ((NN + NSLICE - 1) / NSLICE)   // 6250

typedef unsigned int uint;
typedef unsigned short ushort;
using short8 = __attribute__((ext_vector_type(8))) short;
using f32x4  = __attribute__((ext_vector_type(4))) float;

__device__ inline ushort f2bf(float f) {              // RNE round to bf16
    uint u = __float_as_uint(f);
    u += 0x7fffu + ((u >> 16) & 1u);
    return (ushort)(u >> 16);
}
__device__ inline float bf2f(ushort h) { return __uint_as_float(((uint)h) << 16); }

__global__ void zero_k(int* __restrict__ p, int n) {
    int i = blockIdx.x * blockDim.x + threadIdx.x;
    if (i < n) p[i] = 0;
}

// XCD-sliced bucket fill: block (chunk = bid>>3, slice = bid&7).
// Each chunk is scanned by 8 blocks; each processes only dst in its slice.
// Slice colp footprint = 6250*256B = 1.6MB -> fits one XCD's 4MB L2, so the
// ~16 scattered 4B stores per node row coalesce in L2 before write-back.
// Correct under ANY block->XCD mapping (slice ownership is by blockIdx).
__global__ void fill_sliced_k(const int* __restrict__ src, const int* __restrict__ dst,
                              int* __restrict__ deg, int* __restrict__ colp, int e) {
    int slice = blockIdx.x & (NSLICE - 1);
    int chunk = blockIdx.x >> 3;
    int nch   = gridDim.x >> 3;
    int lo = slice * SLICE_N, hi = lo + SLICE_N;
    for (int i = chunk * blockDim.x + threadIdx.x; i < e; i += nch * blockDim.x) {
        int d = dst[i];
        if (d >= lo && d < hi) {
            int slot = atomicAdd(&deg[d], 1);
            if (slot < PAD) colp[(size_t)d * PAD + slot] = src[i];
        }
    }
}

// ---------- fused gather-mean + MFMA linear ----------
// Block = 64 rows. Phase 1: wave w gathers rows w*16..w*16+15 into As (fp32).
// Phase 2: O[64x64] = As @ W^T via mfma_f32_16x16x32_bf16, split-bf16 3-term.
// Layouts (R5-verified): A row=lane&15, k=(lane>>4)*8+i; B col=lane&15 same k;
//                        C col=lane&15, row=(lane>>4)*4+reg.
__global__ __launch_bounds__(256) void layer_fused_k(const float* __restrict__ x,
                                                     const int* __restrict__ deg,
                                                     const int* __restrict__ colp,
                                                     const float* __restrict__ Wg,
                                                     float* __restrict__ O, int n) {
    __shared__ float As[64][NF + 4];             // row stride 272B: frag b128 reads ~2-way banked
    int tid = threadIdx.x;
    int lane = tid & 63, w = tid >> 6;
    int row0 = blockIdx.x * 64;

    // ---- phase 1: gather-mean into LDS ----
    #pragma unroll
    for (int rr = 0; rr < 16; ++rr) {
        int r = w * 16 + rr;
        int row = row0 + r;
        float val = 0.0f;
        if (row < n) {
            int dg = deg[row];
            if (dg > PAD) dg = PAD;              // slot-guarded fill dropped the rest
            const int* cp = colp + (size_t)row * PAD;
            float acc0 = x[(size_t)row * NF + lane];   // self loop
            float acc1 = 0.f, acc2 = 0.f, acc3 = 0.f;
            int e = 0;
            for (; e + 8 <= dg; e += 8) {        // 8 gathers in flight, 4 chains
                int4 ca = ((const int4*)cp)[(e >> 2)];
                int4 cb = ((const int4*)cp)[(e >> 2) + 1];
                float v0 = x[(size_t)ca.x * NF + lane];
                float v1 = x[(size_t)ca.y * NF + lane];
                float v2 = x[(size_t)ca.z * NF + lane];
                float v3 = x[(size_t)ca.w * NF + lane];
                float v4 = x[(size_t)cb.x * NF + lane];
                float v5 = x[(size_t)cb.y * NF + lane];
                float v6 = x[(size_t)cb.z * NF + lane];
                float v7 = x[(size_t)cb.w * NF + lane];
                acc0 += v0; acc1 += v1; acc2 += v2; acc3 += v3;
                acc0 += v4; acc1 += v5; acc2 += v6; acc3 += v7;
            }
            for (; e < dg; ++e)
                acc0 += x[(size_t)cp[e] * NF + lane];
            val = (acc0 + acc1 + acc2 + acc3) * (1.0f / (float)(dg + 1));
        }
        As[r][lane] = val;                       // 64 consecutive floats: conflict-free
    }
    __syncthreads();

    // ---- phase 2: MFMA ----
    int m = lane & 15, g = lane >> 4;
    int ko = g * 8;
    const float* ar = &As[w * 16 + m][0];

    float af[16];
    *(float4*)(af + 0)  = *(const float4*)(ar + ko);
    *(float4*)(af + 4)  = *(const float4*)(ar + ko + 4);
    *(float4*)(af + 8)  = *(const float4*)(ar + 32 + ko);
    *(float4*)(af + 12) = *(const float4*)(ar + 32 + ko + 4);

    short8 ah0, al0, ah1, al1;
    #pragma unroll
    for (int i = 0; i < 8; ++i) {
        ushort h = f2bf(af[i]);
        ah0[i] = (short)h; al0[i] = (short)f2bf(af[i] - bf2f(h));
        ushort h2 = f2bf(af[8 + i]);
        ah1[i] = (short)h2; al1[i] = (short)f2bf(af[8 + i] - bf2f(h2));
    }

    f32x4 acc[4];
    #pragma unroll
    for (int t = 0; t < 4; ++t) {
        const float* wr = Wg + (size_t)(t * 16 + m) * NF;   // B col = W row (W^T)
        float wf[16];
        *(float4*)(wf + 0)  = *(const float4*)(wr + ko);
        *(float4*)(wf + 4)  = *(const float4*)(wr + ko + 4);
        *(float4*)(wf + 8)  = *(const float4*)(wr + 32 + ko);
        *(float4*)(wf + 12) = *(const float4*)(wr + 32 + ko + 4);
        short8 bh0, bl0, bh1, bl1;
        #pragma unroll
        for (int i = 0; i < 8; ++i) {
            ushort h = f2bf(wf[i]);
            bh0[i] = (short)h; bl0[i] = (short)f2bf(wf[i] - bf2f(h));
            ushort h2 = f2bf(wf[8 + i]);
            bh1[i] = (short)h2; bl1[i] = (short)f2bf(wf[8 + i] - bf2f(h2));
        }
        f32x4 c = {0.f, 0.f, 0.f, 0.f};
        c = __builtin_amdgcn_mfma_f32_16x16x32_bf16(ah0, bh0, c, 0, 0, 0);
        c = __builtin_amdgcn_mfma_f32_16x16x32_bf16(ah1, bh1, c, 0, 0, 0);
        c = __builtin_amdgcn_mfma_f32_16x16x32_bf16(al0, bh0, c, 0, 0, 0);
        c = __builtin_amdgcn_mfma_f32_16x16x32_bf16(al1, bh1, c, 0, 0, 0);
        c = __builtin_amdgcn_mfma_f32_16x16x32_bf16(ah0, bl0, c, 0, 0, 0);
        c = __builtin_amdgcn_mfma_f32_16x16x32_bf16(ah1, bl1, c, 0, 0, 0);
        acc[t] = c;
    }

    #pragma unroll
    for (int t = 0; t < 4; ++t) {
        #pragma unroll
        for (int r = 0; r < 4; ++r) {
            int orow = row0 + w * 16 + g * 4 + r;
            if (orow < n) O[(size_t)orow * NF + t * 16 + m] = acc[t][r];
        }
    }
}

extern "C" void kernel_launch(void* const* d_in, const int* in_sizes, int n_in,
                              void* d_out, int out_size, void* d_ws, size_t ws_size,
                              hipStream_t stream) {
    const float* x_in = (const float*)d_in[0];
    const int*   edge = (const int*)d_in[1];      // [2][NE]
    const float* Wg   = (const float*)d_in[2];    // [NL][64][64]
    float* out = (float*)d_out;

    // ws: deg [0,256K) | colp [256K, 256K+12.8M) | bufA [14M, 14M+12.8M)
    int*   deg  = (int*)d_ws;
    int*   colp = (int*)((char*)d_ws + (256 << 10));
    float* bufA = (float*)((char*)d_ws + (14 << 20));

    zero_k<<<(NN + 255) / 256, 256, 0, stream>>>(deg, NN);
    fill_sliced_k<<<256 * NSLICE, 256, 0, stream>>>(edge, edge + NE, deg, colp, NE);

    const int lb = (NN + 63) / 64;   // 782 blocks
    // x -> out -> bufA -> out  (no aliasing within a layer; final lands in d_out)
    layer_fused_k<<<lb, 256, 0, stream>>>(x_in, deg, colp, Wg + 0 * NF * NF, out,  NN);
    layer_fused_k<<<lb, 256, 0, stream>>>(out,  deg, colp, Wg + 1 * NF * NF, bufA, NN);
    layer_fused_k<<<lb, 256, 0, stream>>>(bufA, deg, colp, Wg + 2 * NF * NF, out,  NN);
}

// Round 11
// 269.756 us; speedup vs baseline: 1.1897x; 1.1897x over previous
//
#include <hip/hip_runtime.h>

#define NN 50000
#define NE 800000
#define NF 64
#define NL 3
#define PAD 64

typedef unsigned int uint;
typedef unsigned short ushort;
using short8 = __attribute__((ext_vector_type(8))) short;
using f32x4  = __attribute__((ext_vector_type(4))) float;

__device__ inline ushort f2bf(float f) {              // RNE round to bf16
    uint u = __float_as_uint(f);
    u += 0x7fffu + ((u >> 16) & 1u);
    return (ushort)(u >> 16);
}
__device__ inline float bf2f(ushort h) { return __uint_as_float(((uint)h) << 16); }

__global__ void zero_k(int* __restrict__ p, int n) {
    int i = blockIdx.x * blockDim.x + threadIdx.x;
    if (i < n) p[i] = 0;
}

// SoA bucket fill: colp[slot*NN + node]. Slot-s stores land in a 200KB plane;
// hot planes (slots 0..~25, ~5MB, Poisson(16) degrees) stay L2-resident so
// dirty sectors accumulate ~16 stores before write-back (vs R5 AoS: every
// 4B store evicted its own 64B sector -> WRITE_SIZE 48MB).
__global__ void fill_k(const int* __restrict__ src, const int* __restrict__ dst,
                       int* __restrict__ deg, int* __restrict__ colp, int e) {
    int i = blockIdx.x * blockDim.x + threadIdx.x;
    if (i < e) {
        int d = dst[i];
        int slot = atomicAdd(&deg[d], 1);
        if (slot < PAD) colp[(size_t)slot * NN + d] = src[i];   // guarded; P(deg>64)~0
    }
}

// ---------- gather-mean: agg[row] = (x[row] + sum_s x[colp[s*NN+row]]) / (deg+1) ----------
// wave per node, lane per feature; 8 gathers in flight, 4 acc chains.
// colp reads are wave-uniform 4B loads (HW broadcasts same-address).
__global__ __launch_bounds__(256) void gather_k(const float* __restrict__ x,
                                                const int* __restrict__ deg,
                                                const int* __restrict__ colp,
                                                float* __restrict__ agg, int n) {
    int tid = threadIdx.x;
    int lane = tid & 63;
    int row = blockIdx.x * 4 + (tid >> 6);
    if (row >= n) return;
    int dg = deg[row];
    if (dg > PAD) dg = PAD;
    float invd = 1.0f / (float)(dg + 1);
    const int* cp = colp + row;                // stride NN between slots
    float acc0 = x[(size_t)row * NF + lane];   // self loop
    float acc1 = 0.f, acc2 = 0.f, acc3 = 0.f;
    int e = 0;
    for (; e + 8 <= dg; e += 8) {
        int s0 = cp[(size_t)(e + 0) * NN];
        int s1 = cp[(size_t)(e + 1) * NN];
        int s2 = cp[(size_t)(e + 2) * NN];
        int s3 = cp[(size_t)(e + 3) * NN];
        int s4 = cp[(size_t)(e + 4) * NN];
        int s5 = cp[(size_t)(e + 5) * NN];
        int s6 = cp[(size_t)(e + 6) * NN];
        int s7 = cp[(size_t)(e + 7) * NN];
        float v0 = x[(size_t)s0 * NF + lane];
        float v1 = x[(size_t)s1 * NF + lane];
        float v2 = x[(size_t)s2 * NF + lane];
        float v3 = x[(size_t)s3 * NF + lane];
        float v4 = x[(size_t)s4 * NF + lane];
        float v5 = x[(size_t)s5 * NF + lane];
        float v6 = x[(size_t)s6 * NF + lane];
        float v7 = x[(size_t)s7 * NF + lane];
        acc0 += v0; acc1 += v1; acc2 += v2; acc3 += v3;
        acc0 += v4; acc1 += v5; acc2 += v6; acc3 += v7;
    }
    for (; e < dg; ++e)
        acc0 += x[(size_t)cp[(size_t)e * NN] * NF + lane];
    agg[(size_t)row * NF + lane] = (acc0 + acc1 + acc2 + acc3) * invd;
}

// ---------- GEMM: O[n x 64] = A[n x 64] @ W^T (W row-major [out][in]) ----------
// mfma_f32_16x16x32_bf16, split-bf16 3 terms (R5-verified, absmax 6.1e-5).
// Layouts: A row=lane&15, k=(lane>>4)*8+i; B col=lane&15 same k;
//          C col=lane&15, row=(lane>>4)*4+reg.
__global__ __launch_bounds__(256) void gemm_k(const float* __restrict__ A,
                                              const float* __restrict__ Wg,
                                              float* __restrict__ O, int n) {
    int tid = threadIdx.x;
    int lane = tid & 63, w = tid >> 6;
    int m = lane & 15, g = lane >> 4;
    int ko = g * 8;
    int row0 = blockIdx.x * 64;

    int arow = row0 + w * 16 + m;
    if (arow > n - 1) arow = n - 1;            // tail: clamp loads, mask stores
    const float* ar = A + (size_t)arow * NF;

    float af[16];
    *(float4*)(af + 0)  = *(const float4*)(ar + ko);
    *(float4*)(af + 4)  = *(const float4*)(ar + ko + 4);
    *(float4*)(af + 8)  = *(const float4*)(ar + 32 + ko);
    *(float4*)(af + 12) = *(const float4*)(ar + 32 + ko + 4);

    short8 ah0, al0, ah1, al1;
    #pragma unroll
    for (int i = 0; i < 8; ++i) {
        ushort h = f2bf(af[i]);
        ah0[i] = (short)h; al0[i] = (short)f2bf(af[i] - bf2f(h));
        ushort h2 = f2bf(af[8 + i]);
        ah1[i] = (short)h2; al1[i] = (short)f2bf(af[8 + i] - bf2f(h2));
    }

    f32x4 acc[4];
    #pragma unroll
    for (int t = 0; t < 4; ++t) {
        const float* wr = Wg + (size_t)(t * 16 + m) * NF;   // B col = W row (W^T)
        float wf[16];
        *(float4*)(wf + 0)  = *(const float4*)(wr + ko);
        *(float4*)(wf + 4)  = *(const float4*)(wr + ko + 4);
        *(float4*)(wf + 8)  = *(const float4*)(wr + 32 + ko);
        *(float4*)(wf + 12) = *(const float4*)(wr + 32 + ko + 4);
        short8 bh0, bl0, bh1, bl1;
        #pragma unroll
        for (int i = 0; i < 8; ++i) {
            ushort h = f2bf(wf[i]);
            bh0[i] = (short)h; bl0[i] = (short)f2bf(wf[i] - bf2f(h));
            ushort h2 = f2bf(wf[8 + i]);
            bh1[i] = (short)h2; bl1[i] = (short)f2bf(wf[8 + i] - bf2f(h2));
        }
        f32x4 c = {0.f, 0.f, 0.f, 0.f};
        c = __builtin_amdgcn_mfma_f32_16x16x32_bf16(ah0, bh0, c, 0, 0, 0);
        c = __builtin_amdgcn_mfma_f32_16x16x32_bf16(ah1, bh1, c, 0, 0, 0);
        c = __builtin_amdgcn_mfma_f32_16x16x32_bf16(al0, bh0, c, 0, 0, 0);
        c = __builtin_amdgcn_mfma_f32_16x16x32_bf16(al1, bh1, c, 0, 0, 0);
        c = __builtin_amdgcn_mfma_f32_16x16x32_bf16(ah0, bl0, c, 0, 0, 0);
        c = __builtin_amdgcn_mfma_f32_16x16x32_bf16(ah1, bl1, c, 0, 0, 0);
        acc[t] = c;
    }

    #pragma unroll
    for (int t = 0; t < 4; ++t) {
        #pragma unroll
        for (int r = 0; r < 4; ++r) {
            int orow = row0 + w * 16 + g * 4 + r;
            if (orow < n) O[(size_t)orow * NF + t * 16 + m] = acc[t][r];
        }
    }
}

extern "C" void kernel_launch(void* const* d_in, const int* in_sizes, int n_in,
                              void* d_out, int out_size, void* d_ws, size_t ws_size,
                              hipStream_t stream) {
    const float* x_in = (const float*)d_in[0];
    const int*   edge = (const int*)d_in[1];      // [2][NE]
    const float* Wg   = (const float*)d_in[2];    // [NL][64][64]
    float* out = (float*)d_out;

    // ws: deg [0,256K) | colp SoA [256K, 256K+12.8M) | agg [14M, 14M+12.8M)
    int*   deg  = (int*)d_ws;
    int*   colp = (int*)((char*)d_ws + (256 << 10));
    float* agg  = (float*)((char*)d_ws + (14 << 20));

    zero_k<<<(NN + 255) / 256, 256, 0, stream>>>(deg, NN);
    fill_k<<<(NE + 255) / 256, 256, 0, stream>>>(edge, edge + NE, deg, colp, NE);

    const int gb = (NN + 3) / 4;        // gather blocks (12500 -> high occupancy)
    const int mb = (NN + 63) / 64;      // gemm blocks

    gather_k<<<gb, 256, 0, stream>>>(x_in, deg, colp, agg, NN);
    gemm_k  <<<mb, 256, 0, stream>>>(agg, Wg + 0 * NF * NF, out, NN);
    gather_k<<<gb, 256, 0, stream>>>(out, deg, colp, agg, NN);
    gemm_k  <<<mb, 256, 0, stream>>>(agg, Wg + 1 * NF * NF, out, NN);
    gather_k<<<gb, 256, 0, stream>>>(out, deg, colp, agg, NN);
    gemm_k  <<<mb, 256, 0, stream>>>(agg, Wg + 2 * NF * NF, out, NN);
}

// Round 13
// 249.953 us; speedup vs baseline: 1.2839x; 1.0792x over previous
//
#include <hip/hip_runtime.h>

#define NN 50000
#define NE 800000
#define NF 64
#define NL 3
#define PAD 64

typedef unsigned int uint;
typedef unsigned short ushort;
using short8 = __attribute__((ext_vector_type(8))) short;
using f32x4  = __attribute__((ext_vector_type(4))) float;

__device__ inline ushort f2bf(float f) {              // RNE round to bf16
    uint u = __float_as_uint(f);
    u += 0x7fffu + ((u >> 16) & 1u);
    return (ushort)(u >> 16);
}
__device__ inline float bf2f(ushort h) { return __uint_as_float(((uint)h) << 16); }

__global__ void zero_k(int* __restrict__ p, int n) {
    int i = blockIdx.x * blockDim.x + threadIdx.x;
    if (i < n) p[i] = 0;
}

// AoS bucket fill (R5 known-good): colp[node*64 + slot]
__global__ void fill_k(const int* __restrict__ src, const int* __restrict__ dst,
                       int* __restrict__ deg, int* __restrict__ colp, int e) {
    int i = blockIdx.x * blockDim.x + threadIdx.x;
    if (i < e) {
        int d = dst[i];
        int slot = atomicAdd(&deg[d], 1);
        if (slot < PAD) colp[(size_t)d * PAD + slot] = src[i];   // P(deg>64)~1e-15
    }
}

// Wc = W3 @ W2 @ W1  (each [out][in] row-major; layer op is X -> X @ W^T, so
// ((X W1^T) W2^T) W3^T = X (W3 W2 W1)^T). One block, 256 threads, ~2us.
__global__ __launch_bounds__(256) void wcomb_k(const float* __restrict__ Wg,
                                               float* __restrict__ Wc) {
    __shared__ float s1[64][65], s2[64][65], st[64][65];
    int tid = threadIdx.x;
    for (int i = tid; i < 64 * 64; i += 256) {
        s1[i >> 6][i & 63] = Wg[i];              // W1
        s2[i >> 6][i & 63] = Wg[4096 + i];       // W2
    }
    __syncthreads();
    for (int i = tid; i < 64 * 64; i += 256) {   // T = W2 @ W1
        int a = i >> 6, c = i & 63;
        float s = 0.f;
        #pragma unroll
        for (int b = 0; b < 64; ++b) s = fmaf(s2[a][b], s1[b][c], s);
        st[a][c] = s;
    }
    __syncthreads();
    for (int i = tid; i < 64 * 64; i += 256) s1[i >> 6][i & 63] = Wg[8192 + i];  // W3
    __syncthreads();
    for (int i = tid; i < 64 * 64; i += 256) {   // Wc = W3 @ T
        int o = i >> 6, c = i & 63;
        float s = 0.f;
        #pragma unroll
        for (int a = 0; a < 64; ++a) s = fmaf(s1[o][a], st[a][c], s);
        Wc[i] = s;
    }
}

// gather-mean, 16 loads in flight: agg[row] = (x[row] + sum x[col]) / (deg+1)
__global__ __launch_bounds__(256) void gather_k(const float* __restrict__ x,
                                                const int* __restrict__ deg,
                                                const int* __restrict__ colp,
                                                float* __restrict__ agg, int n) {
    int tid = threadIdx.x;
    int lane = tid & 63;
    int row = blockIdx.x * 4 + (tid >> 6);
    if (row >= n) return;
    int dg = deg[row];
    if (dg > PAD) dg = PAD;
    float invd = 1.0f / (float)(dg + 1);
    const int4* cp4 = (const int4*)(colp + (size_t)row * PAD);
    float acc0 = x[(size_t)row * NF + lane];     // self loop
    float acc1 = 0.f, acc2 = 0.f, acc3 = 0.f;
    int e = 0;
    for (; e + 16 <= dg; e += 16) {              // 16 gathers in flight
        int4 ia = cp4[(e >> 2) + 0];
        int4 ib = cp4[(e >> 2) + 1];
        int4 ic = cp4[(e >> 2) + 2];
        int4 id = cp4[(e >> 2) + 3];
        float v0  = x[(size_t)ia.x * NF + lane];
        float v1  = x[(size_t)ia.y * NF + lane];
        float v2  = x[(size_t)ia.z * NF + lane];
        float v3  = x[(size_t)ia.w * NF + lane];
        float v4  = x[(size_t)ib.x * NF + lane];
        float v5  = x[(size_t)ib.y * NF + lane];
        float v6  = x[(size_t)ib.z * NF + lane];
        float v7  = x[(size_t)ib.w * NF + lane];
        float v8  = x[(size_t)ic.x * NF + lane];
        float v9  = x[(size_t)ic.y * NF + lane];
        float v10 = x[(size_t)ic.z * NF + lane];
        float v11 = x[(size_t)ic.w * NF + lane];
        float v12 = x[(size_t)id.x * NF + lane];
        float v13 = x[(size_t)id.y * NF + lane];
        float v14 = x[(size_t)id.z * NF + lane];
        float v15 = x[(size_t)id.w * NF + lane];
        acc0 += v0 + v4;  acc1 += v1 + v5;  acc2 += v2 + v6;  acc3 += v3 + v7;
        acc0 += v8 + v12; acc1 += v9 + v13; acc2 += v10 + v14; acc3 += v11 + v15;
    }
    for (; e + 4 <= dg; e += 4) {
        int4 ia = cp4[e >> 2];
        float v0 = x[(size_t)ia.x * NF + lane];
        float v1 = x[(size_t)ia.y * NF + lane];
        float v2 = x[(size_t)ia.z * NF + lane];
        float v3 = x[(size_t)ia.w * NF + lane];
        acc0 += v0; acc1 += v1; acc2 += v2; acc3 += v3;
    }
    for (; e < dg; ++e)
        acc0 += x[(size_t)colp[(size_t)row * PAD + e] * NF + lane];
    agg[(size_t)row * NF + lane] = (acc0 + acc1 + acc2 + acc3) * invd;
}

// O[n x 64] = A[n x 64] @ Wc^T — split-bf16 3-term MFMA (R5-verified layouts).
// Safe IN-PLACE (O==A): each wave reads exactly the 16 rows it writes; waves
// and blocks touch disjoint rows; loads precede stores in wave program order.
__global__ __launch_bounds__(256) void gemm_k(const float* __restrict__ A,
                                              const float* __restrict__ Wg,
                                              float* __restrict__ O, int n) {
    int tid = threadIdx.x;
    int lane = tid & 63, w = tid >> 6;
    int m = lane & 15, g = lane >> 4;
    int ko = g * 8;
    int row0 = blockIdx.x * 64;

    int arow = row0 + w * 16 + m;
    if (arow > n - 1) arow = n - 1;            // tail: clamp loads, mask stores
    const float* ar = A + (size_t)arow * NF;

    float af[16];
    *(float4*)(af + 0)  = *(const float4*)(ar + ko);
    *(float4*)(af + 4)  = *(const float4*)(ar + ko + 4);
    *(float4*)(af + 8)  = *(const float4*)(ar + 32 + ko);
    *(float4*)(af + 12) = *(const float4*)(ar + 32 + ko + 4);

    short8 ah0, al0, ah1, al1;
    #pragma unroll
    for (int i = 0; i < 8; ++i) {
        ushort h = f2bf(af[i]);
        ah0[i] = (short)h; al0[i] = (short)f2bf(af[i] - bf2f(h));
        ushort h2 = f2bf(af[8 + i]);
        ah1[i] = (short)h2; al1[i] = (short)f2bf(af[8 + i] - bf2f(h2));
    }

    f32x4 acc[4];
    #pragma unroll
    for (int t = 0; t < 4; ++t) {
        const float* wr = Wg + (size_t)(t * 16 + m) * NF;   // B col = W row (W^T)
        float wf[16];
        *(float4*)(wf + 0)  = *(const float4*)(wr + ko);
        *(float4*)(wf + 4)  = *(const float4*)(wr + ko + 4);
        *(float4*)(wf + 8)  = *(const float4*)(wr + 32 + ko);
        *(float4*)(wf + 12) = *(const float4*)(wr + 32 + ko + 4);
        short8 bh0, bl0, bh1, bl1;
        #pragma unroll
        for (int i = 0; i < 8; ++i) {
            ushort h = f2bf(wf[i]);
            bh0[i] = (short)h; bl0[i] = (short)f2bf(wf[i] - bf2f(h));
            ushort h2 = f2bf(wf[8 + i]);
            bh1[i] = (short)h2; bl1[i] = (short)f2bf(wf[8 + i] - bf2f(h2));
        }
        f32x4 c = {0.f, 0.f, 0.f, 0.f};
        c = __builtin_amdgcn_mfma_f32_16x16x32_bf16(ah0, bh0, c, 0, 0, 0);
        c = __builtin_amdgcn_mfma_f32_16x16x32_bf16(ah1, bh1, c, 0, 0, 0);
        c = __builtin_amdgcn_mfma_f32_16x16x32_bf16(al0, bh0, c, 0, 0, 0);
        c = __builtin_amdgcn_mfma_f32_16x16x32_bf16(al1, bh1, c, 0, 0, 0);
        c = __builtin_amdgcn_mfma_f32_16x16x32_bf16(ah0, bl0, c, 0, 0, 0);
        c = __builtin_amdgcn_mfma_f32_16x16x32_bf16(ah1, bl1, c, 0, 0, 0);
        acc[t] = c;
    }

    #pragma unroll
    for (int t = 0; t < 4; ++t) {
        #pragma unroll
        for (int r = 0; r < 4; ++r) {
            int orow = row0 + w * 16 + g * 4 + r;
            if (orow < n) O[(size_t)orow * NF + t * 16 + m] = acc[t][r];
        }
    }
}

extern "C" void kernel_launch(void* const* d_in, const int* in_sizes, int n_in,
                              void* d_out, int out_size, void* d_ws, size_t ws_size,
                              hipStream_t stream) {
    const float* x_in = (const float*)d_in[0];
    const int*   edge = (const int*)d_in[1];      // [2][NE]
    const float* Wg   = (const float*)d_in[2];    // [NL][64][64]
    float* out = (float*)d_out;

    // ws: deg [0,200K) | Wc [208K,224K) | colp AoS [256K, 256K+12.8M) | bufA [14M, 26.8M)
    int*   deg  = (int*)d_ws;
    float* Wc   = (float*)((char*)d_ws + (208 << 10));
    int*   colp = (int*)((char*)d_ws + (256 << 10));
    float* bufA = (float*)((char*)d_ws + (14 << 20));

    zero_k <<<(NN + 255) / 256, 256, 0, stream>>>(deg, NN);
    fill_k <<<(NE + 255) / 256, 256, 0, stream>>>(edge, edge + NE, deg, colp, NE);
    wcomb_k<<<1, 256, 0, stream>>>(Wg, Wc);

    const int gb = (NN + 3) / 4;        // 12500 blocks -> high occupancy
    const int mb = (NN + 63) / 64;

    // out = (A^3 x) @ Wc^T : 3 gathers, one (in-place) gemm
    gather_k<<<gb, 256, 0, stream>>>(x_in, deg, colp, out,  NN);
    gather_k<<<gb, 256, 0, stream>>>(out,  deg, colp, bufA, NN);
    gather_k<<<gb, 256, 0, stream>>>(bufA, deg, colp, out,  NN);
    gemm_k  <<<mb, 256, 0, stream>>>(out, Wc, out, NN);
}

// Round 14
// 239.555 us; speedup vs baseline: 1.3397x; 1.0434x over previous
//
#include <hip/hip_runtime.h>

#define NN 50000
#define NE 800000
#define NF 64
#define NL 3
#define PAD 64

typedef unsigned int uint;
typedef unsigned short ushort;
using short8 = __attribute__((ext_vector_type(8))) short;
using f32x4  = __attribute__((ext_vector_type(4))) float;

__device__ inline ushort f2bf(float f) {              // RNE round to bf16
    uint u = __float_as_uint(f);
    u += 0x7fffu + ((u >> 16) & 1u);
    return (ushort)(u >> 16);
}
__device__ inline float bf2f(ushort h) { return __uint_as_float(((uint)h) << 16); }

__global__ void zero_k(int* __restrict__ p, int n) {
    int i = blockIdx.x * blockDim.x + threadIdx.x;
    if (i < n) p[i] = 0;
}

// AoS bucket fill (known-good): colp[node*64 + slot]
__global__ void fill_k(const int* __restrict__ src, const int* __restrict__ dst,
                       int* __restrict__ deg, int* __restrict__ colp, int e) {
    int i = blockIdx.x * blockDim.x + threadIdx.x;
    if (i < e) {
        int d = dst[i];
        int slot = atomicAdd(&deg[d], 1);
        if (slot < PAD) colp[(size_t)d * PAD + slot] = src[i];   // P(deg>64)~1e-15
    }
}

// Wc = W3 @ W2 @ W1 (row-major [out][in]); X -> X @ Wc^T == 3 chained layers.
__global__ __launch_bounds__(256) void wcomb_k(const float* __restrict__ Wg,
                                               float* __restrict__ Wc) {
    __shared__ float s1[64][65], s2[64][65], st[64][65];
    int tid = threadIdx.x;
    for (int i = tid; i < 64 * 64; i += 256) {
        s1[i >> 6][i & 63] = Wg[i];              // W1
        s2[i >> 6][i & 63] = Wg[4096 + i];       // W2
    }
    __syncthreads();
    for (int i = tid; i < 64 * 64; i += 256) {   // T = W2 @ W1
        int a = i >> 6, c = i & 63;
        float s = 0.f;
        #pragma unroll
        for (int b = 0; b < 64; ++b) s = fmaf(s2[a][b], s1[b][c], s);
        st[a][c] = s;
    }
    __syncthreads();
    for (int i = tid; i < 64 * 64; i += 256) s1[i >> 6][i & 63] = Wg[8192 + i];  // W3
    __syncthreads();
    for (int i = tid; i < 64 * 64; i += 256) {   // Wc = W3 @ T
        int o = i >> 6, c = i & 63;
        float s = 0.f;
        #pragma unroll
        for (int a = 0; a < 64; ++a) s = fmaf(s1[o][a], st[a][c], s);
        Wc[i] = s;
    }
}

// gather-mean, float4 form: 16 lanes per row x float4, 4 rows per wave.
// One dwordx4 instruction fetches 4 rows' 256B requests -> 4x fewer vmem
// instructions; 8-deep unroll -> 32 edge-reads in flight per wave.
__global__ __launch_bounds__(256) void gather_k(const float* __restrict__ x,
                                                const int* __restrict__ deg,
                                                const int* __restrict__ colp,
                                                float* __restrict__ agg, int n) {
    const float4* xf4 = (const float4*)x;        // row = 16 float4s
    float4* af4 = (float4*)agg;
    int tid = threadIdx.x;
    int lane = tid & 63;
    int g = lane >> 4;                            // row group within wave (0..3)
    int q = lane & 15;                            // float4 slot within row
    int w = tid >> 6;
    int frow = blockIdx.x * 16 + w * 4 + g;       // NN%16==0: always < n

    int dg = deg[frow];
    if (dg > PAD) dg = PAD;
    float invd = 1.0f / (float)(dg + 1);
    const int4* cp4 = (const int4*)(colp + (size_t)frow * PAD);

    float4 a = xf4[(size_t)frow * 16 + q];        // self loop
    float4 b = {0.f, 0.f, 0.f, 0.f};              // second acc chain

    int dmax = dg;                                 // max deg over the wave's 4 rows
    dmax = max(dmax, __shfl_xor(dmax, 16));
    dmax = max(dmax, __shfl_xor(dmax, 32));

    for (int e = 0; e < dmax; e += 8) {
        // index words: unconditional, always within the row's 64-slot window;
        // poison beyond dg is never dereferenced (loads below are exec-masked)
        int4 ia = cp4[(e >> 2) + 0];
        int4 ib = cp4[(e >> 2) + 1];
        float4 v0 = {0,0,0,0}, v1 = {0,0,0,0}, v2 = {0,0,0,0}, v3 = {0,0,0,0};
        float4 v4 = {0,0,0,0}, v5 = {0,0,0,0}, v6 = {0,0,0,0}, v7 = {0,0,0,0};
        if (e + 0 < dg) v0 = xf4[(size_t)ia.x * 16 + q];
        if (e + 1 < dg) v1 = xf4[(size_t)ia.y * 16 + q];
        if (e + 2 < dg) v2 = xf4[(size_t)ia.z * 16 + q];
        if (e + 3 < dg) v3 = xf4[(size_t)ia.w * 16 + q];
        if (e + 4 < dg) v4 = xf4[(size_t)ib.x * 16 + q];
        if (e + 5 < dg) v5 = xf4[(size_t)ib.y * 16 + q];
        if (e + 6 < dg) v6 = xf4[(size_t)ib.z * 16 + q];
        if (e + 7 < dg) v7 = xf4[(size_t)ib.w * 16 + q];
        a.x += v0.x + v2.x; a.y += v0.y + v2.y; a.z += v0.z + v2.z; a.w += v0.w + v2.w;
        b.x += v1.x + v3.x; b.y += v1.y + v3.y; b.z += v1.z + v3.z; b.w += v1.w + v3.w;
        a.x += v4.x + v6.x; a.y += v4.y + v6.y; a.z += v4.z + v6.z; a.w += v4.w + v6.w;
        b.x += v5.x + v7.x; b.y += v5.y + v7.y; b.z += v5.z + v7.z; b.w += v5.w + v7.w;
    }
    float4 r;
    r.x = (a.x + b.x) * invd; r.y = (a.y + b.y) * invd;
    r.z = (a.z + b.z) * invd; r.w = (a.w + b.w) * invd;
    af4[(size_t)frow * 16 + q] = r;               // wave writes 1KB contiguous
}

// O[n x 64] = A[n x 64] @ Wc^T — split-bf16 3-term MFMA (verified layouts).
// Safe IN-PLACE (O==A): wave reads exactly the 16 rows it writes.
__global__ __launch_bounds__(256) void gemm_k(const float* __restrict__ A,
                                              const float* __restrict__ Wg,
                                              float* __restrict__ O, int n) {
    int tid = threadIdx.x;
    int lane = tid & 63, w = tid >> 6;
    int m = lane & 15, g = lane >> 4;
    int ko = g * 8;
    int row0 = blockIdx.x * 64;

    int arow = row0 + w * 16 + m;
    if (arow > n - 1) arow = n - 1;            // tail: clamp loads, mask stores
    const float* ar = A + (size_t)arow * NF;

    float af[16];
    *(float4*)(af + 0)  = *(const float4*)(ar + ko);
    *(float4*)(af + 4)  = *(const float4*)(ar + ko + 4);
    *(float4*)(af + 8)  = *(const float4*)(ar + 32 + ko);
    *(float4*)(af + 12) = *(const float4*)(ar + 32 + ko + 4);

    short8 ah0, al0, ah1, al1;
    #pragma unroll
    for (int i = 0; i < 8; ++i) {
        ushort h = f2bf(af[i]);
        ah0[i] = (short)h; al0[i] = (short)f2bf(af[i] - bf2f(h));
        ushort h2 = f2bf(af[8 + i]);
        ah1[i] = (short)h2; al1[i] = (short)f2bf(af[8 + i] - bf2f(h2));
    }

    f32x4 acc[4];
    #pragma unroll
    for (int t = 0; t < 4; ++t) {
        const float* wr = Wg + (size_t)(t * 16 + m) * NF;   // B col = W row (W^T)
        float wf[16];
        *(float4*)(wf + 0)  = *(const float4*)(wr + ko);
        *(float4*)(wf + 4)  = *(const float4*)(wr + ko + 4);
        *(float4*)(wf + 8)  = *(const float4*)(wr + 32 + ko);
        *(float4*)(wf + 12) = *(const float4*)(wr + 32 + ko + 4);
        short8 bh0, bl0, bh1, bl1;
        #pragma unroll
        for (int i = 0; i < 8; ++i) {
            ushort h = f2bf(wf[i]);
            bh0[i] = (short)h; bl0[i] = (short)f2bf(wf[i] - bf2f(h));
            ushort h2 = f2bf(wf[8 + i]);
            bh1[i] = (short)h2; bl1[i] = (short)f2bf(wf[8 + i] - bf2f(h2));
        }
        f32x4 c = {0.f, 0.f, 0.f, 0.f};
        c = __builtin_amdgcn_mfma_f32_16x16x32_bf16(ah0, bh0, c, 0, 0, 0);
        c = __builtin_amdgcn_mfma_f32_16x16x32_bf16(ah1, bh1, c, 0, 0, 0);
        c = __builtin_amdgcn_mfma_f32_16x16x32_bf16(al0, bh0, c, 0, 0, 0);
        c = __builtin_amdgcn_mfma_f32_16x16x32_bf16(al1, bh1, c, 0, 0, 0);
        c = __builtin_amdgcn_mfma_f32_16x16x32_bf16(ah0, bl0, c, 0, 0, 0);
        c = __builtin_amdgcn_mfma_f32_16x16x32_bf16(ah1, bl1, c, 0, 0, 0);
        acc[t] = c;
    }

    #pragma unroll
    for (int t = 0; t < 4; ++t) {
        #pragma unroll
        for (int r = 0; r < 4; ++r) {
            int orow = row0 + w * 16 + g * 4 + r;
            if (orow < n) O[(size_t)orow * NF + t * 16 + m] = acc[t][r];
        }
    }
}

extern "C" void kernel_launch(void* const* d_in, const int* in_sizes, int n_in,
                              void* d_out, int out_size, void* d_ws, size_t ws_size,
                              hipStream_t stream) {
    const float* x_in = (const float*)d_in[0];
    const int*   edge = (const int*)d_in[1];      // [2][NE]
    const float* Wg   = (const float*)d_in[2];    // [NL][64][64]
    float* out = (float*)d_out;

    // ws: deg [0,200K) | Wc [208K,224K) | colp AoS [256K, 256K+12.8M) | bufA [14M, 26.8M)
    int*   deg  = (int*)d_ws;
    float* Wc   = (float*)((char*)d_ws + (208 << 10));
    int*   colp = (int*)((char*)d_ws + (256 << 10));
    float* bufA = (float*)((char*)d_ws + (14 << 20));

    zero_k <<<(NN + 255) / 256, 256, 0, stream>>>(deg, NN);
    fill_k <<<(NE + 255) / 256, 256, 0, stream>>>(edge, edge + NE, deg, colp, NE);
    wcomb_k<<<1, 256, 0, stream>>>(Wg, Wc);

    const int gb = NN / 16;             // 3125 blocks, 16 rows/block
    const int mb = (NN + 63) / 64;

    // out = (A^3 x) @ Wc^T : 3 gathers, one (in-place) gemm
    gather_k<<<gb, 256, 0, stream>>>(x_in, deg, colp, out,  NN);
    gather_k<<<gb, 256, 0, stream>>>(out,  deg, colp, bufA, NN);
    gather_k<<<gb, 256, 0, stream>>>(bufA, deg, colp, out,  NN);
    gemm_k  <<<mb, 256, 0, stream>>>(out, Wc, out, NN);
}